// Round 7
// baseline (792.817 us; speedup 1.0000x reference)
//
#include <hip/hip_runtime.h>
#include <math.h>

#define L 768
#define CS 256
#define CZ 128
#define H 8
#define LL (L*L)

typedef __attribute__((ext_vector_type(8))) short bf16x8;
typedef __attribute__((ext_vector_type(4))) float floatx4;

static __device__ __forceinline__ unsigned short f2bf(float f){
  unsigned int u = __float_as_uint(f);
  unsigned int r = (u + 0x7fffu + ((u >> 16) & 1u)) >> 16;
  return (unsigned short)r;
}
static __device__ __forceinline__ float bf2f(unsigned short u){
  return __uint_as_float(((unsigned int)u) << 16);
}

// ---------------- K2: LN(s) fused + projections + rigid transform, 2 rows/block ----------------
__global__ void k_proj(const float* __restrict__ s_raw,
                       const float* __restrict__ lsw, const float* __restrict__ lsb,
                       const float* __restrict__ Wq, const float* __restrict__ Wk, const float* __restrict__ Wv,
                       const float* __restrict__ Wqp, const float* __restrict__ Wkp, const float* __restrict__ Wvp,
                       const float* __restrict__ R, const float* __restrict__ t,
                       float* __restrict__ q, float* __restrict__ kT, float* __restrict__ v,
                       float* __restrict__ qpg, float* __restrict__ kpgT, float* __restrict__ vpg) {
  int i0 = blockIdx.x*2, tid = threadIdx.x;
  __shared__ float srow[2][256];
  __shared__ float red[2][256];
  __shared__ float qraw[2][96], kraw[2][96], vraw[2][192];
  __shared__ float Rl[2][9], tl[2][3];

  float x0 = s_raw[i0*CS + tid];
  float x1 = s_raw[(i0+1)*CS + tid];
  red[0][tid] = x0; red[1][tid] = x1;
  if (tid < 18) Rl[tid/9][tid%9] = R[i0*9 + tid];
  if (tid >= 24 && tid < 30) tl[(tid-24)/3][(tid-24)%3] = t[i0*3 + (tid-24)];
  __syncthreads();
  for (int s2=128; s2>0; s2>>=1){
    if (tid<s2){ red[0][tid]+=red[0][tid+s2]; red[1][tid]+=red[1][tid+s2]; }
    __syncthreads();
  }
  float mean0 = red[0][0]*(1.0f/CS), mean1 = red[1][0]*(1.0f/CS);
  __syncthreads();
  float d0 = x0-mean0, d1 = x1-mean1;
  red[0][tid] = d0*d0; red[1][tid] = d1*d1;
  __syncthreads();
  for (int s2=128; s2>0; s2>>=1){
    if (tid<s2){ red[0][tid]+=red[0][tid+s2]; red[1][tid]+=red[1][tid+s2]; }
    __syncthreads();
  }
  float rstd0 = rsqrtf(red[0][0]*(1.0f/CS) + 1e-5f);
  float rstd1 = rsqrtf(red[1][0]*(1.0f/CS) + 1e-5f);
  float lw = lsw[tid], lb = lsb[tid];
  srow[0][tid] = d0*rstd0*lw + lb;
  srow[1][tid] = d1*rstd1*lw + lb;
  __syncthreads();

  float aq0=0.f, ak0=0.f, av0=0.f, aq1=0.f, ak1=0.f, av1=0.f;
  #pragma unroll 4
  for (int c=0;c<256;c++){
    float s0=srow[0][c], s1=srow[1][c];
    float wq=Wq[c*256+tid], wk=Wk[c*256+tid], wv=Wv[c*256+tid];
    aq0=fmaf(s0,wq,aq0); aq1=fmaf(s1,wq,aq1);
    ak0=fmaf(s0,wk,ak0); ak1=fmaf(s1,wk,ak1);
    av0=fmaf(s0,wv,av0); av1=fmaf(s1,wv,av1);
  }
  q[i0*256+tid]=aq0; q[(i0+1)*256+tid]=aq1;
  kT[(size_t)tid*L + i0]=ak0; kT[(size_t)tid*L + i0+1]=ak1;
  v[i0*256+tid]=av0; v[(i0+1)*256+tid]=av1;
  if (tid < 96){
    float a10=0.f,a20=0.f,a11=0.f,a21=0.f;
    #pragma unroll 4
    for (int c=0;c<256;c++){
      float s0=srow[0][c], s1=srow[1][c];
      float w1=Wqp[c*96+tid], w2=Wkp[c*96+tid];
      a10=fmaf(s0,w1,a10); a11=fmaf(s1,w1,a11);
      a20=fmaf(s0,w2,a20); a21=fmaf(s1,w2,a21);
    }
    qraw[0][tid]=a10; qraw[1][tid]=a11; kraw[0][tid]=a20; kraw[1][tid]=a21;
  }
  if (tid < 192){
    float a30=0.f,a31=0.f;
    #pragma unroll 4
    for (int c=0;c<256;c++){
      float w3=Wvp[c*192+tid];
      a30=fmaf(srow[0][c],w3,a30); a31=fmaf(srow[1][c],w3,a31);
    }
    vraw[0][tid]=a30; vraw[1][tid]=a31;
  }
  __syncthreads();
  #pragma unroll
  for (int rr=0; rr<2; rr++){
    int i = i0 + rr;
    if (tid < 32){
      int b0 = tid*3;
      float px=qraw[rr][b0], py=qraw[rr][b0+1], pz=qraw[rr][b0+2];
      #pragma unroll
      for (int x=0;x<3;x++)
        qpg[i*96 + b0 + x] = Rl[rr][x*3]*px + Rl[rr][x*3+1]*py + Rl[rr][x*3+2]*pz + tl[rr][x];
    } else if (tid < 64){
      int b0 = (tid-32)*3;
      float px=kraw[rr][b0], py=kraw[rr][b0+1], pz=kraw[rr][b0+2];
      #pragma unroll
      for (int x=0;x<3;x++)
        kpgT[(size_t)(b0+x)*L + i] = Rl[rr][x*3]*px + Rl[rr][x*3+1]*py + Rl[rr][x*3+2]*pz + tl[rr][x];
    } else if (tid < 128){
      int b0 = (tid-64)*3;
      float px=vraw[rr][b0], py=vraw[rr][b0+1], pz=vraw[rr][b0+2];
      #pragma unroll
      for (int x=0;x<3;x++)
        vpg[i*192 + b0 + x] = Rl[rr][x*3]*px + Rl[rr][x*3+1]*py + Rl[rr][x*3+2]*pz + tl[rr][x];
    }
  }
}

// ---------------- K_prep ----------------
__global__ void k_prep(const float* __restrict__ lzw, const float* __restrict__ lzb,
                       const float* __restrict__ Wpb, const float* __restrict__ Wpo,
                       unsigned short* __restrict__ Bpack, float* __restrict__ uv) {
  int tid = threadIdx.x, bx = blockIdx.x;
  if (bx == 0){
    if (tid < 48){
      int o = tid;
      float uo = 0.f, vo = 0.f;
      for (int c=0;c<128;c++){
        float W = (o<8) ? Wpb[c*8+o] : ((o<40) ? Wpo[c*32+o-8] : 0.f);
        uo = fmaf(lzw[c], W, uo);
        vo = fmaf(lzb[c], W, vo);
      }
      uv[o] = uo; uv[48+o] = vo;
    }
    return;
  }
  int idx = (bx-1)*256 + tid;
  int jj = idx & 7, lane = (idx>>3)&63, kb = (idx>>9)&3, nt = idx>>11;
  int c = kb*32 + (lane>>4)*8 + jj;
  int o = nt*16 + (lane&15);
  float W = (o<8) ? Wpb[c*8+o] : ((o<40) ? Wpo[c*32+o-8] : 0.f);
  Bpack[idx] = f2bf(lzw[c]*W);
}

// ---------------- K3: z-pass, bf16 MFMA + folded LN ----------------
// z reads: per-lane 256B contiguous (sub*16+kk) + nontemporal (read-once stream)
// via clang ext-vector floatx4 (HIP float4 struct is rejected by the builtin).
__global__ __launch_bounds__(256) void k_zfuse(
    const float* __restrict__ z, const unsigned short* __restrict__ Bpack,
    const float* __restrict__ uv, float* __restrict__ pb, unsigned short* __restrict__ pvb) {
  int i = blockIdx.x, jt = blockIdx.y, tid = threadIdx.x;
  int j0 = jt * 128;
  __shared__ unsigned short znb[128*136];
  __shared__ float smean[128], srstd[128];

  int lane = tid & 63;
  const bf16x8* Bp = (const bf16x8*)Bpack;
  bf16x8 bfr[3][4];
  #pragma unroll
  for (int nt=0; nt<3; nt++)
    #pragma unroll
    for (int kb=0; kb<4; kb++)
      bfr[nt][kb] = Bp[(nt*4+kb)*64 + lane];

  int row = tid >> 1, sub = tid & 1;
  const floatx4* zrow = (const floatx4*)(z + ((size_t)i*L + j0 + row)*CZ);
  float sm = 0.f, sq = 0.f;
  #pragma unroll 8
  for (int kk=0; kk<16; kk++){
    int idx = sub*16 + kk;                  // per-lane contiguous 256B stream
    floatx4 v4 = __builtin_nontemporal_load(&zrow[idx]);
    sm += (v4.x+v4.y)+(v4.z+v4.w);
    sq = fmaf(v4.x,v4.x, fmaf(v4.y,v4.y, fmaf(v4.z,v4.z, fmaf(v4.w,v4.w, sq))));
    ushort4 pk = make_ushort4(f2bf(v4.x), f2bf(v4.y), f2bf(v4.z), f2bf(v4.w));
    *(ushort4*)&znb[row*136 + idx*4] = pk;
  }
  sm += __shfl_xor(sm,1); sq += __shfl_xor(sq,1);
  if (sub == 0){
    float mean = sm*(1.f/128.f);
    float var  = sq*(1.f/128.f) - mean*mean;
    smean[row] = mean; srstd[row] = rsqrtf(var + 1e-5f);
  }
  // NO __syncthreads: each wave's MFMA rows == the rows it staged (same-wave LDS RAW)

  int w = tid >> 6;
  int n16 = lane & 15, quad = lane >> 4;
  #pragma unroll
  for (int mt2=0; mt2<2; mt2++){
    int mt = w*2 + mt2;
    floatx4 acc0 = {0,0,0,0}, acc1 = {0,0,0,0}, acc2 = {0,0,0,0};
    #pragma unroll
    for (int kb=0; kb<4; kb++){
      bf16x8 afrag = *(const bf16x8*)&znb[(mt*16 + n16)*136 + kb*32 + quad*8];
      acc0 = __builtin_amdgcn_mfma_f32_16x16x32_bf16(afrag, bfr[0][kb], acc0, 0,0,0);
      acc1 = __builtin_amdgcn_mfma_f32_16x16x32_bf16(afrag, bfr[1][kb], acc1, 0,0,0);
      acc2 = __builtin_amdgcn_mfma_f32_16x16x32_bf16(afrag, bfr[2][kb], acc2, 0,0,0);
    }
    #pragma unroll
    for (int nt=0; nt<3; nt++){
      int o = nt*16 + n16;
      if (o >= 40) continue;
      float uo = uv[o], vo = uv[48+o];
      const floatx4 acc = (nt==0) ? acc0 : (nt==1) ? acc1 : acc2;
      #pragma unroll
      for (int reg=0; reg<4; reg++){
        int jl = mt*16 + quad*4 + reg;
        int j = j0 + jl;
        float val = srstd[jl]*(acc[reg] - smean[jl]*uo) + vo;
        if (o < 8) pb[(size_t)o*LL + (size_t)i*L + j] = val;
        else {
          int oo = o - 8;
          pvb[(size_t)(oo>>2)*LL*4 + ((size_t)i*L + j)*4 + (oo&3)] = f2bf(val);
        }
      }
    }
  }
}

// ---------------- K4a: logits + softmax + pair-out, 8 i x 1 head per block ----------------
__global__ __launch_bounds__(256) void k_logits(
    const float* __restrict__ q, const float* __restrict__ kT,
    const float* __restrict__ qpg, const float* __restrict__ kpgT,
    float* __restrict__ attn, const unsigned short* __restrict__ pvb,
    const float* __restrict__ point_weights, const float* __restrict__ mask,
    float* __restrict__ su) {
  const int h  = blockIdx.y;
  const int il = threadIdx.x >> 5;
  const int i  = blockIdx.x*8 + il;
  const int jg = threadIdx.x & 31;

  const float pw = log1pf(__expf(point_weights[h]));
  const float mi = mask[i];

  float qreg[32];
  {
    const float4* qr = (const float4*)(q + (size_t)i*256 + h*32);
    #pragma unroll
    for (int c4=0;c4<8;c4++){
      float4 t4 = qr[c4];
      qreg[c4*4+0]=t4.x; qreg[c4*4+1]=t4.y; qreg[c4*4+2]=t4.z; qreg[c4*4+3]=t4.w;
    }
  }
  float qp[12];
  {
    const float4* qr = (const float4*)(qpg + (size_t)i*96 + h*12);
    #pragma unroll
    for (int c4=0;c4<3;c4++){
      float4 t4 = qr[c4];
      qp[c4*4+0]=t4.x; qp[c4*4+1]=t4.y; qp[c4*4+2]=t4.z; qp[c4*4+3]=t4.w;
    }
  }

  const float* kbase  = kT   + (size_t)(h*32)*L + jg*4;
  const float* kpbase = kpgT + (size_t)(h*12)*L + jg*4;
  float* pbrow = attn + (size_t)h*LL + (size_t)i*L + jg*4;

  float lgr[24];
  #pragma unroll
  for (int jt=0; jt<6; jt++){
    const int j0 = jt*128;
    float d0=0.f,d1=0.f,d2=0.f,d3=0.f;
    #pragma unroll
    for (int c=0;c<32;c++){
      float4 kv = *(const float4*)(kbase + (size_t)c*L + j0);
      float qc = qreg[c];
      d0 = fmaf(qc, kv.x, d0); d1 = fmaf(qc, kv.y, d1);
      d2 = fmaf(qc, kv.z, d2); d3 = fmaf(qc, kv.w, d3);
    }
    float s0=0.f,s1=0.f,s2=0.f,s3=0.f;
    #pragma unroll
    for (int pc=0;pc<12;pc++){
      float4 kv = *(const float4*)(kpbase + (size_t)pc*L + j0);
      float qc = qp[pc];
      float e0=qc-kv.x, e1=qc-kv.y, e2=qc-kv.z, e3=qc-kv.w;
      s0=fmaf(e0,e0,s0); s1=fmaf(e1,e1,s1); s2=fmaf(e2,e2,s2); s3=fmaf(e3,e3,s3);
    }
    float4 pb4 = *(const float4*)(pbrow + j0);
    float4 mk4 = *(const float4*)(mask + j0 + jg*4);
    const float SCL = 0.17677669529663687f;
    float l0 = fmaf(d0,SCL,pb4.x) - 0.5f*pw*s0;
    float l1 = fmaf(d1,SCL,pb4.y) - 0.5f*pw*s1;
    float l2 = fmaf(d2,SCL,pb4.z) - 0.5f*pw*s2;
    float l3 = fmaf(d3,SCL,pb4.w) - 0.5f*pw*s3;
    if (mi*mk4.x == 0.f) l0 = -1e9f;
    if (mi*mk4.y == 0.f) l1 = -1e9f;
    if (mi*mk4.z == 0.f) l2 = -1e9f;
    if (mi*mk4.w == 0.f) l3 = -1e9f;
    lgr[jt*4+0]=l0; lgr[jt*4+1]=l1; lgr[jt*4+2]=l2; lgr[jt*4+3]=l3;
  }

  float m = -1e30f;
  #pragma unroll
  for (int u=0;u<24;u++) m = fmaxf(m, lgr[u]);
  #pragma unroll
  for (int d=1; d<32; d<<=1) m = fmaxf(m, __shfl_xor(m, d));
  float ss = 0.f;
  #pragma unroll
  for (int u=0;u<24;u++){ float e = __expf(lgr[u]-m); lgr[u]=e; ss+=e; }
  #pragma unroll
  for (int d=1; d<32; d<<=1) ss += __shfl_xor(ss, d);
  float inv = 1.0f/ss;
  #pragma unroll
  for (int u=0;u<24;u++) lgr[u] *= inv;
  #pragma unroll
  for (int jt=0;jt<6;jt++){
    float4 a4;
    a4.x=lgr[jt*4+0]; a4.y=lgr[jt*4+1]; a4.z=lgr[jt*4+2]; a4.w=lgr[jt*4+3];
    *(float4*)(pbrow + jt*128) = a4;
  }

  // pair-out: 24 coalesced ushort4 loads, weights in registers
  float pq0=0.f,pq1=0.f,pq2=0.f,pq3=0.f;
  const unsigned short* pvrow = pvb + (size_t)h*LL*4 + (size_t)i*L*4 + (size_t)jg*16;
  #pragma unroll
  for (int jt=0;jt<6;jt++){
    #pragma unroll
    for (int r=0;r<4;r++){
      ushort4 pk = *(const ushort4*)(pvrow + jt*512 + r*4);
      float a = lgr[jt*4+r];
      pq0 = fmaf(a, bf2f(pk.x), pq0);
      pq1 = fmaf(a, bf2f(pk.y), pq1);
      pq2 = fmaf(a, bf2f(pk.z), pq2);
      pq3 = fmaf(a, bf2f(pk.w), pq3);
    }
  }
  #pragma unroll
  for (int d=1; d<32; d<<=1){
    pq0 += __shfl_xor(pq0,d); pq1 += __shfl_xor(pq1,d);
    pq2 += __shfl_xor(pq2,d); pq3 += __shfl_xor(pq3,d);
  }
  if (jg == 0){
    float* so = su + (size_t)i*544 + 512 + h*4;
    so[0]=pq0; so[1]=pq1; so[2]=pq2; so[3]=pq3;
  }
}

// ---------------- K4b: PV, j-partitioned output-stationary ----------------
__global__ __launch_bounds__(256) void k_pv(
    const float* __restrict__ attn, const float* __restrict__ v,
    const float* __restrict__ vpg, const float* __restrict__ R,
    const float* __restrict__ t, float* __restrict__ su) {
  const int h = blockIdx.y, i0 = blockIdx.x*8, tid = threadIdx.x;
  __shared__ float awt[8][768];
  __shared__ float pf[8][8][32];
  __shared__ float sptg[8][24];
  __shared__ float sptl[8][24];

  const float* ab = attn + (size_t)h*LL + (size_t)i0*L;
  float* awl = &awt[0][0];
  #pragma unroll
  for (int w2=0; w2<6; w2++){
    float4 t4 = *(const float4*)(ab + (size_t)(w2*256+tid)*4);
    *(float4*)(awl + (w2*256+tid)*4) = t4;
  }
  __syncthreads();

  // family 1: scalar output (32 channels)
  {
    const int c = tid & 31, p = tid >> 5;
    const float* vb = v + h*32 + c;
    float ac0=0.f,ac1=0.f,ac2=0.f,ac3=0.f,ac4=0.f,ac5=0.f,ac6=0.f,ac7=0.f;
    const int jb = p*96;
    #pragma unroll 4
    for (int s=0; s<24; s++){
      const int j = jb + s*4;
      float v0 = vb[(size_t)(j+0)*256];
      float v1 = vb[(size_t)(j+1)*256];
      float v2 = vb[(size_t)(j+2)*256];
      float v3 = vb[(size_t)(j+3)*256];
      float4 a0 = *(const float4*)&awt[0][j];
      float4 a1 = *(const float4*)&awt[1][j];
      float4 a2 = *(const float4*)&awt[2][j];
      float4 a3 = *(const float4*)&awt[3][j];
      float4 a4 = *(const float4*)&awt[4][j];
      float4 a5 = *(const float4*)&awt[5][j];
      float4 a6 = *(const float4*)&awt[6][j];
      float4 a7 = *(const float4*)&awt[7][j];
      ac0 = fmaf(a0.x,v0, fmaf(a0.y,v1, fmaf(a0.z,v2, fmaf(a0.w,v3, ac0))));
      ac1 = fmaf(a1.x,v0, fmaf(a1.y,v1, fmaf(a1.z,v2, fmaf(a1.w,v3, ac1))));
      ac2 = fmaf(a2.x,v0, fmaf(a2.y,v1, fmaf(a2.z,v2, fmaf(a2.w,v3, ac2))));
      ac3 = fmaf(a3.x,v0, fmaf(a3.y,v1, fmaf(a3.z,v2, fmaf(a3.w,v3, ac3))));
      ac4 = fmaf(a4.x,v0, fmaf(a4.y,v1, fmaf(a4.z,v2, fmaf(a4.w,v3, ac4))));
      ac5 = fmaf(a5.x,v0, fmaf(a5.y,v1, fmaf(a5.z,v2, fmaf(a5.w,v3, ac5))));
      ac6 = fmaf(a6.x,v0, fmaf(a6.y,v1, fmaf(a6.z,v2, fmaf(a6.w,v3, ac6))));
      ac7 = fmaf(a7.x,v0, fmaf(a7.y,v1, fmaf(a7.z,v2, fmaf(a7.w,v3, ac7))));
    }
    pf[p][0][c]=ac0; pf[p][1][c]=ac1; pf[p][2][c]=ac2; pf[p][3][c]=ac3;
    pf[p][4][c]=ac4; pf[p][5][c]=ac5; pf[p][6][c]=ac6; pf[p][7][c]=ac7;
  }
  __syncthreads();
  {
    const int ii = tid >> 5, c = tid & 31;
    float a = 0.f;
    #pragma unroll
    for (int p=0;p<8;p++) a += pf[p][ii][c];
    su[(size_t)(i0+ii)*544 + h*32 + c] = a;
  }
  __syncthreads();

  // family 2: point outputs (24 channels), reuses pf
  if (tid < 192){
    const int c = tid % 24, p = tid / 24;
    const float* pb2 = vpg + h*24 + c;
    float ac0=0.f,ac1=0.f,ac2=0.f,ac3=0.f,ac4=0.f,ac5=0.f,ac6=0.f,ac7=0.f;
    const int jb = p*96;
    #pragma unroll 4
    for (int s=0; s<24; s++){
      const int j = jb + s*4;
      float v0 = pb2[(size_t)(j+0)*192];
      float v1 = pb2[(size_t)(j+1)*192];
      float v2 = pb2[(size_t)(j+2)*192];
      float v3 = pb2[(size_t)(j+3)*192];
      float4 a0 = *(const float4*)&awt[0][j];
      float4 a1 = *(const float4*)&awt[1][j];
      float4 a2 = *(const float4*)&awt[2][j];
      float4 a3 = *(const float4*)&awt[3][j];
      float4 a4 = *(const float4*)&awt[4][j];
      float4 a5 = *(const float4*)&awt[5][j];
      float4 a6 = *(const float4*)&awt[6][j];
      float4 a7 = *(const float4*)&awt[7][j];
      ac0 = fmaf(a0.x,v0, fmaf(a0.y,v1, fmaf(a0.z,v2, fmaf(a0.w,v3, ac0))));
      ac1 = fmaf(a1.x,v0, fmaf(a1.y,v1, fmaf(a1.z,v2, fmaf(a1.w,v3, ac1))));
      ac2 = fmaf(a2.x,v0, fmaf(a2.y,v1, fmaf(a2.z,v2, fmaf(a2.w,v3, ac2))));
      ac3 = fmaf(a3.x,v0, fmaf(a3.y,v1, fmaf(a3.z,v2, fmaf(a3.w,v3, ac3))));
      ac4 = fmaf(a4.x,v0, fmaf(a4.y,v1, fmaf(a4.z,v2, fmaf(a4.w,v3, ac4))));
      ac5 = fmaf(a5.x,v0, fmaf(a5.y,v1, fmaf(a5.z,v2, fmaf(a5.w,v3, ac5))));
      ac6 = fmaf(a6.x,v0, fmaf(a6.y,v1, fmaf(a6.z,v2, fmaf(a6.w,v3, ac6))));
      ac7 = fmaf(a7.x,v0, fmaf(a7.y,v1, fmaf(a7.z,v2, fmaf(a7.w,v3, ac7))));
    }
    pf[p][0][c]=ac0; pf[p][1][c]=ac1; pf[p][2][c]=ac2; pf[p][3][c]=ac3;
    pf[p][4][c]=ac4; pf[p][5][c]=ac5; pf[p][6][c]=ac6; pf[p][7][c]=ac7;
  }
  __syncthreads();
  if (tid < 192){
    const int ii = tid / 24, e = tid % 24;
    float a = 0.f;
    #pragma unroll
    for (int p=0;p<8;p++) a += pf[p][ii][e];
    sptg[ii][e] = a;
  }
  __syncthreads();
  if (tid < 192){
    const int ii = tid/24, rem = tid%24, pp = rem/3, y = rem - pp*3;
    const int gi = i0 + ii;
    float acc = 0.f;
    #pragma unroll
    for (int x=0;x<3;x++)
      acc = fmaf(R[gi*9 + x*3 + y], sptg[ii][pp*3+x] - t[gi*3+x], acc);
    sptl[ii][rem] = acc;
    su[(size_t)gi*544 + 256 + h*24 + rem] = acc;
  }
  __syncthreads();
  if (tid < 64){
    const int ii = tid>>3, pp = tid&7;
    const int gi = i0 + ii;
    float x0=sptl[ii][pp*3], x1=sptl[ii][pp*3+1], x2=sptl[ii][pp*3+2];
    su[(size_t)gi*544 + 448 + h*8 + pp] = sqrtf(x0*x0+x1*x1+x2*x2 + 1e-8f);
  }
}

// ---------------- K5: output projection, 4 rows/block ----------------
__global__ void k_out(const float* __restrict__ su_pre, const float* __restrict__ W_out,
                      const float* __restrict__ b_out, const float* __restrict__ mask,
                      float* __restrict__ out) {
  int i0 = blockIdx.x*4, tid = threadIdx.x;
  __shared__ float srow[4][544];
  for (int idx=tid; idx<4*544; idx+=256) srow[idx/544][idx%544] = su_pre[(size_t)i0*544 + idx];
  __syncthreads();
  float b = b_out[tid];
  float a0=b, a1=b, a2=b, a3=b;
  #pragma unroll 4
  for (int c=0;c<544;c++){
    float w = W_out[c*256+tid];
    a0 = fmaf(srow[0][c], w, a0);
    a1 = fmaf(srow[1][c], w, a1);
    a2 = fmaf(srow[2][c], w, a2);
    a3 = fmaf(srow[3][c], w, a3);
  }
  out[(i0+0)*256+tid] = a0 * mask[i0+0];
  out[(i0+1)*256+tid] = a1 * mask[i0+1];
  out[(i0+2)*256+tid] = a2 * mask[i0+2];
  out[(i0+3)*256+tid] = a3 * mask[i0+3];
}

extern "C" void kernel_launch(void* const* d_in, const int* in_sizes, int n_in,
                              void* d_out, int out_size, void* d_ws, size_t ws_size,
                              hipStream_t stream) {
  const float* s    = (const float*)d_in[0];
  const float* z    = (const float*)d_in[1];
  const float* R    = (const float*)d_in[2];
  const float* t    = (const float*)d_in[3];
  const float* mask = (const float*)d_in[4];
  const float* lsw  = (const float*)d_in[5];
  const float* lsb  = (const float*)d_in[6];
  const float* lzw  = (const float*)d_in[7];
  const float* lzb  = (const float*)d_in[8];
  const float* Wq   = (const float*)d_in[9];
  const float* Wk   = (const float*)d_in[10];
  const float* Wv   = (const float*)d_in[11];
  const float* Wpb  = (const float*)d_in[12];
  const float* Wqp  = (const float*)d_in[13];
  const float* Wkp  = (const float*)d_in[14];
  const float* Wvp  = (const float*)d_in[15];
  const float* pwts = (const float*)d_in[16];
  const float* Wpo  = (const float*)d_in[17];
  const float* Wout = (const float*)d_in[18];
  const float* bout = (const float*)d_in[19];

  float* out0 = (float*)d_out;
  float* attn = out0 + (size_t)L*CS;

  float* ws   = (float*)d_ws;
  float* q    = ws;                        size_t off = (size_t)L*CS;
  float* kT   = ws + off;                  off += (size_t)L*CS;
  float* v    = ws + off;                  off += (size_t)L*CS;
  float* qpg  = ws + off;                  off += (size_t)L*96;
  float* kpgT = ws + off;                  off += (size_t)L*96;
  float* vpg  = ws + off;                  off += (size_t)L*192;
  unsigned short* pvb = (unsigned short*)(ws + off); off += (size_t)LL*16;  // LL*32 bf16
  float* su   = ws + off;                  off += (size_t)L*544;
  unsigned short* Bpack = (unsigned short*)(ws + off); off += 3072;
  float* uv   = ws + off;                  off += 96;

  k_prep<<<25, 256, 0, stream>>>(lzw, lzb, Wpb, Wpo, Bpack, uv);
  k_proj<<<L/2, 256, 0, stream>>>(s, lsw, lsb, Wq, Wk, Wv, Wqp, Wkp, Wvp, R, t,
                                  q, kT, v, qpg, kpgT, vpg);
  k_zfuse<<<dim3(L, L/128), 256, 0, stream>>>(z, Bpack, uv, attn, pvb);
  k_logits<<<dim3(L/8, H), 256, 0, stream>>>(q, kT, qpg, kpgT, attn, pvb,
                                             pwts, mask, su);
  k_pv<<<dim3(L/8, H), 256, 0, stream>>>(attn, v, vpg, R, t, su);
  k_out<<<L/4, 256, 0, stream>>>(su, Wout, bout, mask, out0);
}

// Round 8
// 703.994 us; speedup vs baseline: 1.1262x; 1.1262x over previous
//
#include <hip/hip_runtime.h>
#include <math.h>

#define L 768
#define CS 256
#define CZ 128
#define H 8
#define LL (L*L)

typedef __attribute__((ext_vector_type(8))) short bf16x8;
typedef __attribute__((ext_vector_type(4))) float floatx4;

static __device__ __forceinline__ unsigned short f2bf(float f){
  unsigned int u = __float_as_uint(f);
  unsigned int r = (u + 0x7fffu + ((u >> 16) & 1u)) >> 16;
  return (unsigned short)r;
}
static __device__ __forceinline__ float bf2f(unsigned short u){
  return __uint_as_float(((unsigned int)u) << 16);
}

// ---------------- K2: LN(s) fused + projections + rigid transform, 2 rows/block ----------------
__global__ void k_proj(const float* __restrict__ s_raw,
                       const float* __restrict__ lsw, const float* __restrict__ lsb,
                       const float* __restrict__ Wq, const float* __restrict__ Wk, const float* __restrict__ Wv,
                       const float* __restrict__ Wqp, const float* __restrict__ Wkp, const float* __restrict__ Wvp,
                       const float* __restrict__ R, const float* __restrict__ t,
                       float* __restrict__ q, float* __restrict__ kT, float* __restrict__ v,
                       float* __restrict__ qpg, float* __restrict__ kpgT, float* __restrict__ vpg) {
  int i0 = blockIdx.x*2, tid = threadIdx.x;
  __shared__ float srow[2][256];
  __shared__ float red[2][256];
  __shared__ float qraw[2][96], kraw[2][96], vraw[2][192];
  __shared__ float Rl[2][9], tl[2][3];

  float x0 = s_raw[i0*CS + tid];
  float x1 = s_raw[(i0+1)*CS + tid];
  red[0][tid] = x0; red[1][tid] = x1;
  if (tid < 18) Rl[tid/9][tid%9] = R[i0*9 + tid];
  if (tid >= 24 && tid < 30) tl[(tid-24)/3][(tid-24)%3] = t[i0*3 + (tid-24)];
  __syncthreads();
  for (int s2=128; s2>0; s2>>=1){
    if (tid<s2){ red[0][tid]+=red[0][tid+s2]; red[1][tid]+=red[1][tid+s2]; }
    __syncthreads();
  }
  float mean0 = red[0][0]*(1.0f/CS), mean1 = red[1][0]*(1.0f/CS);
  __syncthreads();
  float d0 = x0-mean0, d1 = x1-mean1;
  red[0][tid] = d0*d0; red[1][tid] = d1*d1;
  __syncthreads();
  for (int s2=128; s2>0; s2>>=1){
    if (tid<s2){ red[0][tid]+=red[0][tid+s2]; red[1][tid]+=red[1][tid+s2]; }
    __syncthreads();
  }
  float rstd0 = rsqrtf(red[0][0]*(1.0f/CS) + 1e-5f);
  float rstd1 = rsqrtf(red[1][0]*(1.0f/CS) + 1e-5f);
  float lw = lsw[tid], lb = lsb[tid];
  srow[0][tid] = d0*rstd0*lw + lb;
  srow[1][tid] = d1*rstd1*lw + lb;
  __syncthreads();

  float aq0=0.f, ak0=0.f, av0=0.f, aq1=0.f, ak1=0.f, av1=0.f;
  #pragma unroll 4
  for (int c=0;c<256;c++){
    float s0=srow[0][c], s1=srow[1][c];
    float wq=Wq[c*256+tid], wk=Wk[c*256+tid], wv=Wv[c*256+tid];
    aq0=fmaf(s0,wq,aq0); aq1=fmaf(s1,wq,aq1);
    ak0=fmaf(s0,wk,ak0); ak1=fmaf(s1,wk,ak1);
    av0=fmaf(s0,wv,av0); av1=fmaf(s1,wv,av1);
  }
  q[i0*256+tid]=aq0; q[(i0+1)*256+tid]=aq1;
  kT[(size_t)tid*L + i0]=ak0; kT[(size_t)tid*L + i0+1]=ak1;
  v[i0*256+tid]=av0; v[(i0+1)*256+tid]=av1;
  if (tid < 96){
    float a10=0.f,a20=0.f,a11=0.f,a21=0.f;
    #pragma unroll 4
    for (int c=0;c<256;c++){
      float s0=srow[0][c], s1=srow[1][c];
      float w1=Wqp[c*96+tid], w2=Wkp[c*96+tid];
      a10=fmaf(s0,w1,a10); a11=fmaf(s1,w1,a11);
      a20=fmaf(s0,w2,a20); a21=fmaf(s1,w2,a21);
    }
    qraw[0][tid]=a10; qraw[1][tid]=a11; kraw[0][tid]=a20; kraw[1][tid]=a21;
  }
  if (tid < 192){
    float a30=0.f,a31=0.f;
    #pragma unroll 4
    for (int c=0;c<256;c++){
      float w3=Wvp[c*192+tid];
      a30=fmaf(srow[0][c],w3,a30); a31=fmaf(srow[1][c],w3,a31);
    }
    vraw[0][tid]=a30; vraw[1][tid]=a31;
  }
  __syncthreads();
  #pragma unroll
  for (int rr=0; rr<2; rr++){
    int i = i0 + rr;
    if (tid < 32){
      int b0 = tid*3;
      float px=qraw[rr][b0], py=qraw[rr][b0+1], pz=qraw[rr][b0+2];
      #pragma unroll
      for (int x=0;x<3;x++)
        qpg[i*96 + b0 + x] = Rl[rr][x*3]*px + Rl[rr][x*3+1]*py + Rl[rr][x*3+2]*pz + tl[rr][x];
    } else if (tid < 64){
      int b0 = (tid-32)*3;
      float px=kraw[rr][b0], py=kraw[rr][b0+1], pz=kraw[rr][b0+2];
      #pragma unroll
      for (int x=0;x<3;x++)
        kpgT[(size_t)(b0+x)*L + i] = Rl[rr][x*3]*px + Rl[rr][x*3+1]*py + Rl[rr][x*3+2]*pz + tl[rr][x];
    } else if (tid < 128){
      int b0 = (tid-64)*3;
      float px=vraw[rr][b0], py=vraw[rr][b0+1], pz=vraw[rr][b0+2];
      #pragma unroll
      for (int x=0;x<3;x++)
        vpg[i*192 + b0 + x] = Rl[rr][x*3]*px + Rl[rr][x*3+1]*py + Rl[rr][x*3+2]*pz + tl[rr][x];
    }
  }
}

// ---------------- K_prep ----------------
// Bpack layout serves as the MFMA *A* operand (o-rows x c-K) after the operand
// swap in k_zfuse — indexing is identical to the old B-pack, no change needed.
__global__ void k_prep(const float* __restrict__ lzw, const float* __restrict__ lzb,
                       const float* __restrict__ Wpb, const float* __restrict__ Wpo,
                       unsigned short* __restrict__ Bpack, float* __restrict__ uv) {
  int tid = threadIdx.x, bx = blockIdx.x;
  if (bx == 0){
    if (tid < 48){
      int o = tid;
      float uo = 0.f, vo = 0.f;
      for (int c=0;c<128;c++){
        float W = (o<8) ? Wpb[c*8+o] : ((o<40) ? Wpo[c*32+o-8] : 0.f);
        uo = fmaf(lzw[c], W, uo);
        vo = fmaf(lzb[c], W, vo);
      }
      uv[o] = uo; uv[48+o] = vo;
    }
    return;
  }
  int idx = (bx-1)*256 + tid;
  int jj = idx & 7, lane = (idx>>3)&63, kb = (idx>>9)&3, nt = idx>>11;
  int c = kb*32 + (lane>>4)*8 + jj;
  int o = nt*16 + (lane&15);
  float W = (o<8) ? Wpb[c*8+o] : ((o<40) ? Wpo[c*32+o-8] : 0.f);
  Bpack[idx] = f2bf(lzw[c]*W);
}

// ---------------- K3: z-pass, bf16 MFMA + folded LN ----------------
// Operand-SWAPPED MFMA: acc = mfma(W_frag, z_frag) -> C' = o x j.
// Stores become 16-lane contiguous 64B (pb) / 128B-span (pvb) segments instead
// of 4B scatter at 2.36MB stride (round-7 profile: all pipes idle, stall-bound).
// Staging pattern reverted to the round-5 interleaved float4 (NT hurt: 205us).
__global__ __launch_bounds__(256) void k_zfuse(
    const float* __restrict__ z, const unsigned short* __restrict__ Bpack,
    const float* __restrict__ uv, float* __restrict__ pb, unsigned short* __restrict__ pvb) {
  int i = blockIdx.x, jt = blockIdx.y, tid = threadIdx.x;
  int j0 = jt * 128;
  __shared__ unsigned short znb[128*136];
  __shared__ float smean[128], srstd[128];

  int lane = tid & 63;
  const bf16x8* Bp = (const bf16x8*)Bpack;
  bf16x8 wfr[3][4];
  #pragma unroll
  for (int nt=0; nt<3; nt++)
    #pragma unroll
    for (int kb=0; kb<4; kb++)
      wfr[nt][kb] = Bp[(nt*4+kb)*64 + lane];

  int row = tid >> 1, sub = tid & 1;
  const float4* zrow = (const float4*)(z + ((size_t)i*L + j0 + row)*CZ);
  float sm = 0.f, sq = 0.f;
  #pragma unroll 8
  for (int kk=0; kk<16; kk++){
    float4 v4 = zrow[sub + 2*kk];
    sm += (v4.x+v4.y)+(v4.z+v4.w);
    sq = fmaf(v4.x,v4.x, fmaf(v4.y,v4.y, fmaf(v4.z,v4.z, fmaf(v4.w,v4.w, sq))));
    ushort4 pk = make_ushort4(f2bf(v4.x), f2bf(v4.y), f2bf(v4.z), f2bf(v4.w));
    *(ushort4*)&znb[row*136 + (sub+2*kk)*4] = pk;
  }
  sm += __shfl_xor(sm,1); sq += __shfl_xor(sq,1);
  if (sub == 0){
    float mean = sm*(1.f/128.f);
    float var  = sq*(1.f/128.f) - mean*mean;
    smean[row] = mean; srstd[row] = rsqrtf(var + 1e-5f);
  }
  // NO __syncthreads: wave w's j-tiles (w*2+jj2)*16+n16 == rows w*32..w*32+31,
  // exactly the rows this wave staged (same-wave LDS RAW).

  int w = tid >> 6;
  int n16 = lane & 15, quad = lane >> 4;

  // hoist per-thread uv values: o = nt*16 + quad*4 + reg
  float uo_r[3][4], vo_r[3][4];
  #pragma unroll
  for (int nt=0; nt<3; nt++)
    #pragma unroll
    for (int reg=0; reg<4; reg++){
      int o = nt*16 + quad*4 + reg;
      uo_r[nt][reg] = (o < 48) ? uv[o] : 0.f;
      vo_r[nt][reg] = (o < 48) ? uv[48+o] : 0.f;
    }

  #pragma unroll
  for (int jj2=0; jj2<2; jj2++){
    int jl = (w*2 + jj2)*16 + n16;          // per-lane j within the 128-tile
    floatx4 acc0 = {0,0,0,0}, acc1 = {0,0,0,0}, acc2 = {0,0,0,0};
    #pragma unroll
    for (int kb=0; kb<4; kb++){
      bf16x8 zfrag = *(const bf16x8*)&znb[jl*136 + kb*32 + quad*8];
      acc0 = __builtin_amdgcn_mfma_f32_16x16x32_bf16(wfr[0][kb], zfrag, acc0, 0,0,0);
      acc1 = __builtin_amdgcn_mfma_f32_16x16x32_bf16(wfr[1][kb], zfrag, acc1, 0,0,0);
      acc2 = __builtin_amdgcn_mfma_f32_16x16x32_bf16(wfr[2][kb], zfrag, acc2, 0,0,0);
    }
    float mean = smean[jl], rstd = srstd[jl];
    int j = j0 + jl;
    #pragma unroll
    for (int nt=0; nt<3; nt++){
      const floatx4 acc = (nt==0) ? acc0 : (nt==1) ? acc1 : acc2;
      #pragma unroll
      for (int reg=0; reg<4; reg++){
        int o = nt*16 + quad*4 + reg;       // C' row
        if (o >= 40) continue;              // uniform per quad (nt=2, quad>=2)
        float val = rstd*(acc[reg] - mean*uo_r[nt][reg]) + vo_r[nt][reg];
        if (o < 8) pb[(size_t)o*LL + (size_t)i*L + j] = val;
        else {
          int oo = o - 8;
          pvb[(size_t)(oo>>2)*LL*4 + ((size_t)i*L + j)*4 + (oo&3)] = f2bf(val);
        }
      }
    }
  }
}

// ---------------- K4a: logits + softmax + pair-out, 8 i x 1 head per block ----------------
__global__ __launch_bounds__(256) void k_logits(
    const float* __restrict__ q, const float* __restrict__ kT,
    const float* __restrict__ qpg, const float* __restrict__ kpgT,
    float* __restrict__ attn, const unsigned short* __restrict__ pvb,
    const float* __restrict__ point_weights, const float* __restrict__ mask,
    float* __restrict__ su) {
  const int h  = blockIdx.y;
  const int il = threadIdx.x >> 5;
  const int i  = blockIdx.x*8 + il;
  const int jg = threadIdx.x & 31;

  const float pw = log1pf(__expf(point_weights[h]));
  const float mi = mask[i];

  float qreg[32];
  {
    const float4* qr = (const float4*)(q + (size_t)i*256 + h*32);
    #pragma unroll
    for (int c4=0;c4<8;c4++){
      float4 t4 = qr[c4];
      qreg[c4*4+0]=t4.x; qreg[c4*4+1]=t4.y; qreg[c4*4+2]=t4.z; qreg[c4*4+3]=t4.w;
    }
  }
  float qp[12];
  {
    const float4* qr = (const float4*)(qpg + (size_t)i*96 + h*12);
    #pragma unroll
    for (int c4=0;c4<3;c4++){
      float4 t4 = qr[c4];
      qp[c4*4+0]=t4.x; qp[c4*4+1]=t4.y; qp[c4*4+2]=t4.z; qp[c4*4+3]=t4.w;
    }
  }

  const float* kbase  = kT   + (size_t)(h*32)*L + jg*4;
  const float* kpbase = kpgT + (size_t)(h*12)*L + jg*4;
  float* pbrow = attn + (size_t)h*LL + (size_t)i*L + jg*4;

  float lgr[24];
  #pragma unroll
  for (int jt=0; jt<6; jt++){
    const int j0 = jt*128;
    float d0=0.f,d1=0.f,d2=0.f,d3=0.f;
    #pragma unroll
    for (int c=0;c<32;c++){
      float4 kv = *(const float4*)(kbase + (size_t)c*L + j0);
      float qc = qreg[c];
      d0 = fmaf(qc, kv.x, d0); d1 = fmaf(qc, kv.y, d1);
      d2 = fmaf(qc, kv.z, d2); d3 = fmaf(qc, kv.w, d3);
    }
    float s0=0.f,s1=0.f,s2=0.f,s3=0.f;
    #pragma unroll
    for (int pc=0;pc<12;pc++){
      float4 kv = *(const float4*)(kpbase + (size_t)pc*L + j0);
      float qc = qp[pc];
      float e0=qc-kv.x, e1=qc-kv.y, e2=qc-kv.z, e3=qc-kv.w;
      s0=fmaf(e0,e0,s0); s1=fmaf(e1,e1,s1); s2=fmaf(e2,e2,s2); s3=fmaf(e3,e3,s3);
    }
    float4 pb4 = *(const float4*)(pbrow + j0);
    float4 mk4 = *(const float4*)(mask + j0 + jg*4);
    const float SCL = 0.17677669529663687f;
    float l0 = fmaf(d0,SCL,pb4.x) - 0.5f*pw*s0;
    float l1 = fmaf(d1,SCL,pb4.y) - 0.5f*pw*s1;
    float l2 = fmaf(d2,SCL,pb4.z) - 0.5f*pw*s2;
    float l3 = fmaf(d3,SCL,pb4.w) - 0.5f*pw*s3;
    if (mi*mk4.x == 0.f) l0 = -1e9f;
    if (mi*mk4.y == 0.f) l1 = -1e9f;
    if (mi*mk4.z == 0.f) l2 = -1e9f;
    if (mi*mk4.w == 0.f) l3 = -1e9f;
    lgr[jt*4+0]=l0; lgr[jt*4+1]=l1; lgr[jt*4+2]=l2; lgr[jt*4+3]=l3;
  }

  float m = -1e30f;
  #pragma unroll
  for (int u=0;u<24;u++) m = fmaxf(m, lgr[u]);
  #pragma unroll
  for (int d=1; d<32; d<<=1) m = fmaxf(m, __shfl_xor(m, d));
  float ss = 0.f;
  #pragma unroll
  for (int u=0;u<24;u++){ float e = __expf(lgr[u]-m); lgr[u]=e; ss+=e; }
  #pragma unroll
  for (int d=1; d<32; d<<=1) ss += __shfl_xor(ss, d);
  float inv = 1.0f/ss;
  #pragma unroll
  for (int u=0;u<24;u++) lgr[u] *= inv;
  #pragma unroll
  for (int jt=0;jt<6;jt++){
    float4 a4;
    a4.x=lgr[jt*4+0]; a4.y=lgr[jt*4+1]; a4.z=lgr[jt*4+2]; a4.w=lgr[jt*4+3];
    *(float4*)(pbrow + jt*128) = a4;
  }

  // pair-out: 24 coalesced ushort4 loads, weights in registers
  float pq0=0.f,pq1=0.f,pq2=0.f,pq3=0.f;
  const unsigned short* pvrow = pvb + (size_t)h*LL*4 + (size_t)i*L*4 + (size_t)jg*16;
  #pragma unroll
  for (int jt=0;jt<6;jt++){
    #pragma unroll
    for (int r=0;r<4;r++){
      ushort4 pk = *(const ushort4*)(pvrow + jt*512 + r*4);
      float a = lgr[jt*4+r];
      pq0 = fmaf(a, bf2f(pk.x), pq0);
      pq1 = fmaf(a, bf2f(pk.y), pq1);
      pq2 = fmaf(a, bf2f(pk.z), pq2);
      pq3 = fmaf(a, bf2f(pk.w), pq3);
    }
  }
  #pragma unroll
  for (int d=1; d<32; d<<=1){
    pq0 += __shfl_xor(pq0,d); pq1 += __shfl_xor(pq1,d);
    pq2 += __shfl_xor(pq2,d); pq3 += __shfl_xor(pq3,d);
  }
  if (jg == 0){
    float* so = su + (size_t)i*544 + 512 + h*4;
    so[0]=pq0; so[1]=pq1; so[2]=pq2; so[3]=pq3;
  }
}

// ---------------- K4b: PV, j-partitioned output-stationary ----------------
__global__ __launch_bounds__(256) void k_pv(
    const float* __restrict__ attn, const float* __restrict__ v,
    const float* __restrict__ vpg, const float* __restrict__ R,
    const float* __restrict__ t, float* __restrict__ su) {
  const int h = blockIdx.y, i0 = blockIdx.x*8, tid = threadIdx.x;
  __shared__ float awt[8][768];
  __shared__ float pf[8][8][32];
  __shared__ float sptg[8][24];
  __shared__ float sptl[8][24];

  const float* ab = attn + (size_t)h*LL + (size_t)i0*L;
  float* awl = &awt[0][0];
  #pragma unroll
  for (int w2=0; w2<6; w2++){
    float4 t4 = *(const float4*)(ab + (size_t)(w2*256+tid)*4);
    *(float4*)(awl + (w2*256+tid)*4) = t4;
  }
  __syncthreads();

  // family 1: scalar output (32 channels)
  {
    const int c = tid & 31, p = tid >> 5;
    const float* vb = v + h*32 + c;
    float ac0=0.f,ac1=0.f,ac2=0.f,ac3=0.f,ac4=0.f,ac5=0.f,ac6=0.f,ac7=0.f;
    const int jb = p*96;
    #pragma unroll 4
    for (int s=0; s<24; s++){
      const int j = jb + s*4;
      float v0 = vb[(size_t)(j+0)*256];
      float v1 = vb[(size_t)(j+1)*256];
      float v2 = vb[(size_t)(j+2)*256];
      float v3 = vb[(size_t)(j+3)*256];
      float4 a0 = *(const float4*)&awt[0][j];
      float4 a1 = *(const float4*)&awt[1][j];
      float4 a2 = *(const float4*)&awt[2][j];
      float4 a3 = *(const float4*)&awt[3][j];
      float4 a4 = *(const float4*)&awt[4][j];
      float4 a5 = *(const float4*)&awt[5][j];
      float4 a6 = *(const float4*)&awt[6][j];
      float4 a7 = *(const float4*)&awt[7][j];
      ac0 = fmaf(a0.x,v0, fmaf(a0.y,v1, fmaf(a0.z,v2, fmaf(a0.w,v3, ac0))));
      ac1 = fmaf(a1.x,v0, fmaf(a1.y,v1, fmaf(a1.z,v2, fmaf(a1.w,v3, ac1))));
      ac2 = fmaf(a2.x,v0, fmaf(a2.y,v1, fmaf(a2.z,v2, fmaf(a2.w,v3, ac2))));
      ac3 = fmaf(a3.x,v0, fmaf(a3.y,v1, fmaf(a3.z,v2, fmaf(a3.w,v3, ac3))));
      ac4 = fmaf(a4.x,v0, fmaf(a4.y,v1, fmaf(a4.z,v2, fmaf(a4.w,v3, ac4))));
      ac5 = fmaf(a5.x,v0, fmaf(a5.y,v1, fmaf(a5.z,v2, fmaf(a5.w,v3, ac5))));
      ac6 = fmaf(a6.x,v0, fmaf(a6.y,v1, fmaf(a6.z,v2, fmaf(a6.w,v3, ac6))));
      ac7 = fmaf(a7.x,v0, fmaf(a7.y,v1, fmaf(a7.z,v2, fmaf(a7.w,v3, ac7))));
    }
    pf[p][0][c]=ac0; pf[p][1][c]=ac1; pf[p][2][c]=ac2; pf[p][3][c]=ac3;
    pf[p][4][c]=ac4; pf[p][5][c]=ac5; pf[p][6][c]=ac6; pf[p][7][c]=ac7;
  }
  __syncthreads();
  {
    const int ii = tid >> 5, c = tid & 31;
    float a = 0.f;
    #pragma unroll
    for (int p=0;p<8;p++) a += pf[p][ii][c];
    su[(size_t)(i0+ii)*544 + h*32 + c] = a;
  }
  __syncthreads();

  // family 2: point outputs (24 channels), reuses pf
  if (tid < 192){
    const int c = tid % 24, p = tid / 24;
    const float* pb2 = vpg + h*24 + c;
    float ac0=0.f,ac1=0.f,ac2=0.f,ac3=0.f,ac4=0.f,ac5=0.f,ac6=0.f,ac7=0.f;
    const int jb = p*96;
    #pragma unroll 4
    for (int s=0; s<24; s++){
      const int j = jb + s*4;
      float v0 = pb2[(size_t)(j+0)*192];
      float v1 = pb2[(size_t)(j+1)*192];
      float v2 = pb2[(size_t)(j+2)*192];
      float v3 = pb2[(size_t)(j+3)*192];
      float4 a0 = *(const float4*)&awt[0][j];
      float4 a1 = *(const float4*)&awt[1][j];
      float4 a2 = *(const float4*)&awt[2][j];
      float4 a3 = *(const float4*)&awt[3][j];
      float4 a4 = *(const float4*)&awt[4][j];
      float4 a5 = *(const float4*)&awt[5][j];
      float4 a6 = *(const float4*)&awt[6][j];
      float4 a7 = *(const float4*)&awt[7][j];
      ac0 = fmaf(a0.x,v0, fmaf(a0.y,v1, fmaf(a0.z,v2, fmaf(a0.w,v3, ac0))));
      ac1 = fmaf(a1.x,v0, fmaf(a1.y,v1, fmaf(a1.z,v2, fmaf(a1.w,v3, ac1))));
      ac2 = fmaf(a2.x,v0, fmaf(a2.y,v1, fmaf(a2.z,v2, fmaf(a2.w,v3, ac2))));
      ac3 = fmaf(a3.x,v0, fmaf(a3.y,v1, fmaf(a3.z,v2, fmaf(a3.w,v3, ac3))));
      ac4 = fmaf(a4.x,v0, fmaf(a4.y,v1, fmaf(a4.z,v2, fmaf(a4.w,v3, ac4))));
      ac5 = fmaf(a5.x,v0, fmaf(a5.y,v1, fmaf(a5.z,v2, fmaf(a5.w,v3, ac5))));
      ac6 = fmaf(a6.x,v0, fmaf(a6.y,v1, fmaf(a6.z,v2, fmaf(a6.w,v3, ac6))));
      ac7 = fmaf(a7.x,v0, fmaf(a7.y,v1, fmaf(a7.z,v2, fmaf(a7.w,v3, ac7))));
    }
    pf[p][0][c]=ac0; pf[p][1][c]=ac1; pf[p][2][c]=ac2; pf[p][3][c]=ac3;
    pf[p][4][c]=ac4; pf[p][5][c]=ac5; pf[p][6][c]=ac6; pf[p][7][c]=ac7;
  }
  __syncthreads();
  if (tid < 192){
    const int ii = tid / 24, e = tid % 24;
    float a = 0.f;
    #pragma unroll
    for (int p=0;p<8;p++) a += pf[p][ii][e];
    sptg[ii][e] = a;
  }
  __syncthreads();
  if (tid < 192){
    const int ii = tid/24, rem = tid%24, pp = rem/3, y = rem - pp*3;
    const int gi = i0 + ii;
    float acc = 0.f;
    #pragma unroll
    for (int x=0;x<3;x++)
      acc = fmaf(R[gi*9 + x*3 + y], sptg[ii][pp*3+x] - t[gi*3+x], acc);
    sptl[ii][rem] = acc;
    su[(size_t)gi*544 + 256 + h*24 + rem] = acc;
  }
  __syncthreads();
  if (tid < 64){
    const int ii = tid>>3, pp = tid&7;
    const int gi = i0 + ii;
    float x0=sptl[ii][pp*3], x1=sptl[ii][pp*3+1], x2=sptl[ii][pp*3+2];
    su[(size_t)gi*544 + 448 + h*8 + pp] = sqrtf(x0*x0+x1*x1+x2*x2 + 1e-8f);
  }
}

// ---------------- K5: output projection, 4 rows/block ----------------
__global__ void k_out(const float* __restrict__ su_pre, const float* __restrict__ W_out,
                      const float* __restrict__ b_out, const float* __restrict__ mask,
                      float* __restrict__ out) {
  int i0 = blockIdx.x*4, tid = threadIdx.x;
  __shared__ float srow[4][544];
  for (int idx=tid; idx<4*544; idx+=256) srow[idx/544][idx%544] = su_pre[(size_t)i0*544 + idx];
  __syncthreads();
  float b = b_out[tid];
  float a0=b, a1=b, a2=b, a3=b;
  #pragma unroll 4
  for (int c=0;c<544;c++){
    float w = W_out[c*256+tid];
    a0 = fmaf(srow[0][c], w, a0);
    a1 = fmaf(srow[1][c], w, a1);
    a2 = fmaf(srow[2][c], w, a2);
    a3 = fmaf(srow[3][c], w, a3);
  }
  out[(i0+0)*256+tid] = a0 * mask[i0+0];
  out[(i0+1)*256+tid] = a1 * mask[i0+1];
  out[(i0+2)*256+tid] = a2 * mask[i0+2];
  out[(i0+3)*256+tid] = a3 * mask[i0+3];
}

extern "C" void kernel_launch(void* const* d_in, const int* in_sizes, int n_in,
                              void* d_out, int out_size, void* d_ws, size_t ws_size,
                              hipStream_t stream) {
  const float* s    = (const float*)d_in[0];
  const float* z    = (const float*)d_in[1];
  const float* R    = (const float*)d_in[2];
  const float* t    = (const float*)d_in[3];
  const float* mask = (const float*)d_in[4];
  const float* lsw  = (const float*)d_in[5];
  const float* lsb  = (const float*)d_in[6];
  const float* lzw  = (const float*)d_in[7];
  const float* lzb  = (const float*)d_in[8];
  const float* Wq   = (const float*)d_in[9];
  const float* Wk   = (const float*)d_in[10];
  const float* Wv   = (const float*)d_in[11];
  const float* Wpb  = (const float*)d_in[12];
  const float* Wqp  = (const float*)d_in[13];
  const float* Wkp  = (const float*)d_in[14];
  const float* Wvp  = (const float*)d_in[15];
  const float* pwts = (const float*)d_in[16];
  const float* Wpo  = (const float*)d_in[17];
  const float* Wout = (const float*)d_in[18];
  const float* bout = (const float*)d_in[19];

  float* out0 = (float*)d_out;
  float* attn = out0 + (size_t)L*CS;

  float* ws   = (float*)d_ws;
  float* q    = ws;                        size_t off = (size_t)L*CS;
  float* kT   = ws + off;                  off += (size_t)L*CS;
  float* v    = ws + off;                  off += (size_t)L*CS;
  float* qpg  = ws + off;                  off += (size_t)L*96;
  float* kpgT = ws + off;                  off += (size_t)L*96;
  float* vpg  = ws + off;                  off += (size_t)L*192;
  unsigned short* pvb = (unsigned short*)(ws + off); off += (size_t)LL*16;  // LL*32 bf16
  float* su   = ws + off;                  off += (size_t)L*544;
  unsigned short* Bpack = (unsigned short*)(ws + off); off += 3072;
  float* uv   = ws + off;                  off += 96;

  k_prep<<<25, 256, 0, stream>>>(lzw, lzb, Wpb, Wpo, Bpack, uv);
  k_proj<<<L/2, 256, 0, stream>>>(s, lsw, lsb, Wq, Wk, Wv, Wqp, Wkp, Wvp, R, t,
                                  q, kT, v, qpg, kpgT, vpg);
  k_zfuse<<<dim3(L, L/128), 256, 0, stream>>>(z, Bpack, uv, attn, pvb);
  k_logits<<<dim3(L/8, H), 256, 0, stream>>>(q, kT, qpg, kpgT, attn, pvb,
                                             pwts, mask, su);
  k_pv<<<dim3(L/8, H), 256, 0, stream>>>(attn, v, vpg, R, t, su);
  k_out<<<L/4, 256, 0, stream>>>(su, Wout, bout, mask, out0);
}